// Round 6
// baseline (84.333 us; speedup 1.0000x reference)
//
#include <hip/hip_runtime.h>
#include <hip/hip_bf16.h>
#include <stdint.h>

// out = softmax(x1, -1) @ x2
// x1: [1,16,2048,2048] fp32, x2: [1,16,2048,64] fp32, out: [1,16,2048,64] fp32
//
// R6: occupancy attack. R1/R3/R4/R5 all ran 512 blocks = 2 blocks/CU; every
// schedule variant landed >= 64us (~65% of stream BW) -> phase duty-cycle is
// the bound, not intra-loop scheduling. R6: 16-row tiles, 128-thread blocks,
// grid 2048 = 8 blocks/CU = 16 waves/CU (4/SIMD). Independent barrier groups
// interleave load/compute phases across blocks; memory stays busy.
//  - pT (16x128 bf16, 4KB, R1's XOR swizzle) is the only LDS tile
//  - B-fragments direct from L2-resident x2t (R5-verified coalesced path),
//    issued BEFORE the barrier so MFMA phase has no global latency
//  - row-sum via fp32 VALU + shfl_xor + rsum_lds broadcast (no ones-MFMA)
//  - x1 nontemporal (dense 128B/instr segments; keeps x2t hot in L2)

#define H_  16
#define S_  2048
#define D_  64
#define QT  64    // fallback kernel tile
#define QT2 16    // main kernel rows per block
#define NT  (S_ / 128)

typedef short bf16x8 __attribute__((ext_vector_type(8)));  // 8 bf16 (4 VGPRs)
typedef float f32x4  __attribute__((ext_vector_type(4)));

__device__ __forceinline__ uint16_t f2bf(float f) {  // round-to-nearest-even
  uint32_t u = __builtin_bit_cast(uint32_t, f);
  u += 0x7fffu + ((u >> 16) & 1u);
  return (uint16_t)(u >> 16);
}

// Pre-kernel: x2 [H][S][D] fp32  ->  x2t [H][D][S] bf16 (k-contiguous rows)
__global__ __launch_bounds__(256) void vtrans_kernel(const float* __restrict__ x2,
                                                     uint16_t* __restrict__ x2t) {
  __shared__ float t[D_][64 + 1];  // +1 pad: bank-conflict-free transpose
  const int h  = blockIdx.x >> 5;
  const int k0 = (blockIdx.x & 31) << 6;  // 64-k tile
  const float* src = x2 + ((size_t)h * S_ + k0) * D_;
#pragma unroll
  for (int p = 0; p < 4; ++p) {
    int flat = p * 1024 + threadIdx.x * 4;
    int k = flat >> 6, d = flat & 63;
    float4 v = *(const float4*)(src + (size_t)k * D_ + d);
    t[d + 0][k] = v.x; t[d + 1][k] = v.y; t[d + 2][k] = v.z; t[d + 3][k] = v.w;
  }
  __syncthreads();
  uint16_t* dst = x2t + (size_t)h * D_ * S_ + k0;
#pragma unroll
  for (int p = 0; p < 4; ++p) {
    int flat = p * 1024 + threadIdx.x * 4;
    int d = flat >> 6, k = flat & 63;
    ushort4 o;
    o.x = f2bf(t[d][k + 0]); o.y = f2bf(t[d][k + 1]);
    o.z = f2bf(t[d][k + 2]); o.w = f2bf(t[d][k + 3]);
    *(ushort4*)(dst + (size_t)d * S_ + k) = o;
  }
}

// ---------------- main kernel: 8 blocks/CU, 2 waves/block ----------------
__global__ __launch_bounds__(128, 4) void smm_hiocc(const float* __restrict__ x1,
                                                    const uint16_t* __restrict__ x2t,
                                                    float* __restrict__ out) {
  __shared__ __attribute__((aligned(16))) uint16_t pT[QT2][128];  // 4KB, swizzled
  __shared__ float rsum_lds[QT2];

  // bijective XCD swizzle: 2048 blocks = 8 XCDs x 256 contiguous (2 heads/XCD)
  const int bid  = (blockIdx.x & 7) * 256 + (blockIdx.x >> 3);
  const int tid  = threadIdx.x;
  const int lane = tid & 63;
  const int w    = tid >> 6;                 // wave 0,1 -> col half
  const int h    = bid >> 7;                 // 128 blocks per head
  const int q0   = (bid & 127) * QT2;

  const int r16  = lane & 15;                // fragment row/col
  const int kg   = lane >> 4;                // fragment k-group (0..3)

  // staging: thread t -> row t>>3 (fixed all iters), seg t&7
  const int srow = tid >> 3;                 // 0..15
  const int sseg = tid & 7;
  const float* ap = x1 + ((size_t)(h * S_ + q0 + srow)) * S_ + sseg * 4;

  // B: wave w covers cols w*32 .. w*32+31 (2 col-tiles of 16)
  const uint16_t* bb  = x2t + (size_t)h * D_ * S_ + (size_t)(w * 32 + r16) * S_ + kg * 8;
  const uint16_t* b1b = bb + (size_t)16 * S_;

  f32x4 acc0 = (f32x4){0.f, 0.f, 0.f, 0.f};
  f32x4 acc1 = (f32x4){0.f, 0.f, 0.f, 0.f};
  float rsum = 0.f;                          // running sum for row srow, this k-subset

  for (int kt = 0; kt < 16; ++kt) {
    const int kbase = kt * 128;

    // ---- issue all global loads up front (x1 NT + 8 B-fragments) ----
    f32x4 a0 = __builtin_nontemporal_load((const f32x4*)(ap + kbase));
    f32x4 a1 = __builtin_nontemporal_load((const f32x4*)(ap + kbase + 32));
    f32x4 a2 = __builtin_nontemporal_load((const f32x4*)(ap + kbase + 64));
    f32x4 a3 = __builtin_nontemporal_load((const f32x4*)(ap + kbase + 96));
    uint4 bv0[4], bv1[4];
#pragma unroll
    for (int ks = 0; ks < 4; ++ks) {
      bv0[ks] = *(const uint4*)(bb  + kbase + ks * 32);
      bv1[ks] = *(const uint4*)(b1b + kbase + ks * 32);
    }

    // ---- exp + pack + swizzled LDS write (waits on a0..a3) ----
    {
      f32x4 av[4] = {a0, a1, a2, a3};
#pragma unroll
      for (int p = 0; p < 4; ++p) {
        float e0 = __expf(av[p][0]), e1 = __expf(av[p][1]);
        float e2 = __expf(av[p][2]), e3 = __expf(av[p][3]);
        rsum += (e0 + e1) + (e2 + e3);
        uint32_t lo = (uint32_t)f2bf(e0) | ((uint32_t)f2bf(e1) << 16);
        uint32_t hi = (uint32_t)f2bf(e2) | ((uint32_t)f2bf(e3) << 16);
        int k = sseg * 4 + p * 32;
        int byteoff = (k * 2) ^ ((srow & 15) << 4);   // R1's XOR swizzle
        *(uint2*)((char*)(&pT[srow][0]) + byteoff) = make_uint2(lo, hi);
      }
    }
    __syncthreads();

    // ---- MFMA phase: A from LDS, B already in regs ----
#pragma unroll
    for (int ks = 0; ks < 4; ++ks) {
      int kb = ks * 64 + kg * 16;
      bf16x8 af = *(const bf16x8*)((const char*)(&pT[r16][0]) + (kb ^ (r16 << 4)));
      acc0 = __builtin_amdgcn_mfma_f32_16x16x32_bf16(af, __builtin_bit_cast(bf16x8, bv0[ks]), acc0, 0, 0, 0);
      acc1 = __builtin_amdgcn_mfma_f32_16x16x32_bf16(af, __builtin_bit_cast(bf16x8, bv1[ks]), acc1, 0, 0, 0);
    }
    __syncthreads();   // WAR: fragment reads done before next iter's writes
  }

  // ---- row sums: 8 staging threads per row -> rsum_lds ----
  rsum += __shfl_xor(rsum, 1);
  rsum += __shfl_xor(rsum, 2);
  rsum += __shfl_xor(rsum, 4);
  if ((lane & 7) == 0) rsum_lds[srow] = rsum;
  __syncthreads();

  // ---- epilogue: normalize, store fp32 (NT: write-once) ----
  // D layout: col = lane&15, row = kg*4 + reg  [refcheck-verified R1/R4/R5]
  float* op = out + ((size_t)(h * S_ + q0)) * D_;
#pragma unroll
  for (int j = 0; j < 4; ++j) {
    int row = kg * 4 + j;
    float rs = 1.0f / rsum_lds[row];
    float o0 = acc0[j] * rs;
    float o1 = acc1[j] * rs;
    __builtin_nontemporal_store(o0, op + (size_t)row * D_ + w * 32 + r16);
    __builtin_nontemporal_store(o1, op + (size_t)row * D_ + w * 32 + 16 + r16);
  }
}

// ---------------- fallback (tiny workspace): R1 LDS kernel ----------------
__global__ __launch_bounds__(256) void smm_lds(const float* __restrict__ x1,
                                               const float* __restrict__ x2,
                                               float* __restrict__ out) {
  __shared__ __attribute__((aligned(16))) uint16_t pT[QT][128];
  __shared__ __attribute__((aligned(16))) uint16_t vT[D_][128];

  const int tid  = threadIdx.x;
  const int lane = tid & 63;
  const int w    = tid >> 6;
  const int h    = blockIdx.x >> 5;
  const int q0   = (blockIdx.x & 31) * QT;

  f32x4 acc[4];
  f32x4 accS;
#pragma unroll
  for (int c = 0; c < 4; ++c) acc[c] = (f32x4){0.f, 0.f, 0.f, 0.f};
  accS = (f32x4){0.f, 0.f, 0.f, 0.f};

  bf16x8 ones;
  {
    short v = ((lane & 15) == 0) ? (short)0x3F80 : (short)0;
#pragma unroll
    for (int e = 0; e < 8; ++e) ones[e] = v;
  }

  const float* x1p = x1 + ((size_t)h * S_ + q0) * S_;
  const int prow = tid >> 5;
  const int pk4  = (tid & 31) << 2;
  const int arow = lane & 15;
  const int kgrp = lane >> 4;

  for (int kt = 0; kt < NT; ++kt) {
    __syncthreads();
#pragma unroll
    for (int p = 0; p < 8; ++p) {
      int r = prow + p * 8;
      float4 v = *(const float4*)(x1p + (size_t)r * S_ + kt * 128 + pk4);
      uint32_t lo = (uint32_t)f2bf(__expf(v.x)) | ((uint32_t)f2bf(__expf(v.y)) << 16);
      uint32_t hi = (uint32_t)f2bf(__expf(v.z)) | ((uint32_t)f2bf(__expf(v.w)) << 16);
      int byteoff = (pk4 * 2) ^ ((r & 15) << 4);
      *(uint2*)((char*)(&pT[r][0]) + byteoff) = make_uint2(lo, hi);
    }
    {
      int dd = tid & 63;
      int kgq = tid >> 6;
      const float* src = x2 + ((size_t)h * S_ + kt * 128) * D_ + dd;
#pragma unroll
      for (int p = 0; p < 4; ++p) {
        int kb = p * 32 + kgq * 8;
        uint16_t tmp[8];
#pragma unroll
        for (int j = 0; j < 8; ++j) tmp[j] = f2bf(src[(size_t)(kb + j) * D_]);
        int byteoff = (kb * 2) ^ ((dd & 15) << 4);
        *(uint4*)((char*)(&vT[dd][0]) + byteoff) = *(uint4*)tmp;
      }
    }
    __syncthreads();
#pragma unroll
    for (int ks = 0; ks < 4; ++ks) {
      int kb = ks * 64 + kgrp * 16;
      int ar = w * 16 + arow;
      bf16x8 a = *(const bf16x8*)((const char*)(&pT[ar][0]) + (kb ^ (arow << 4)));
      accS = __builtin_amdgcn_mfma_f32_16x16x32_bf16(a, ones, accS, 0, 0, 0);
#pragma unroll
      for (int c = 0; c < 4; ++c) {
        int bc = c * 16 + arow;
        bf16x8 b = *(const bf16x8*)((const char*)(&vT[bc][0]) + (kb ^ (arow << 4)));
        acc[c] = __builtin_amdgcn_mfma_f32_16x16x32_bf16(a, b, acc[c], 0, 0, 0);
      }
    }
  }

  float* op = out + ((size_t)h * S_ + q0 + w * 16) * D_;
#pragma unroll
  for (int j = 0; j < 4; ++j) {
    float s = __shfl(accS[j], lane & 48);
    float rs = 1.0f / s;
    int row = (lane >> 4) * 4 + j;
#pragma unroll
    for (int c = 0; c < 4; ++c) {
      op[(size_t)row * D_ + c * 16 + (lane & 15)] = acc[c][j] * rs;
    }
  }
}

extern "C" void kernel_launch(void* const* d_in, const int* in_sizes, int n_in,
                              void* d_out, int out_size, void* d_ws, size_t ws_size,
                              hipStream_t stream) {
  const float* x1 = (const float*)d_in[0];
  const float* x2 = (const float*)d_in[1];
  float* out      = (float*)d_out;
  uint16_t* x2t   = (uint16_t*)d_ws;

  const size_t need = (size_t)H_ * D_ * S_ * sizeof(uint16_t);  // 4 MiB
  if (ws_size >= need) {
    vtrans_kernel<<<dim3(H_ * (S_ / 64)), dim3(256), 0, stream>>>(x2, x2t);
    smm_hiocc<<<dim3(H_ * (S_ / QT2)), dim3(128), 0, stream>>>(x1, x2t, out);
  } else {
    smm_lds<<<dim3(H_ * (S_ / QT)), dim3(256), 0, stream>>>(x1, x2, out);
  }
}

// Round 7
// 75.839 us; speedup vs baseline: 1.1120x; 1.1120x over previous
//
#include <hip/hip_runtime.h>
#include <hip/hip_bf16.h>
#include <stdint.h>

// out = softmax(x1, -1) @ x2
// x1: [1,16,2048,2048] fp32, x2: [1,16,2048,64] fp32, out: [1,16,2048,64] fp32
//
// R7: traffic model. R1/R3's 64.4us == 268MB(x1) + 128MB(V re-staged, L2-miss
// because the x1 stream floods L2) at 6.3 TB/s. Fix = amortize V over more
// rows/block: QT 64->128 halves V traffic to 64MB. Structure is R1's proven
// serial {barrier, stage x1+V, barrier, MFMA} loop, scaled to 512 threads
// (8 waves -> same 8 waves/CU as R1). Grid 256 = 16 heads x 16 row-blocks,
// XCD-swizzled so each XCD's hot x2t slice = 2 heads = 512KB.

#define H_  16
#define S_  2048
#define D_  64
#define QT  128   // rows per block (16 per wave, 8 waves)
#define QTF 64    // fallback kernel tile
#define KT  128
#define NT  (S_ / KT)  // 16

typedef short bf16x8 __attribute__((ext_vector_type(8)));  // 8 bf16 (4 VGPRs)
typedef float f32x4  __attribute__((ext_vector_type(4)));

__device__ __forceinline__ uint16_t f2bf(float f) {  // round-to-nearest-even
  uint32_t u = __builtin_bit_cast(uint32_t, f);
  u += 0x7fffu + ((u >> 16) & 1u);
  return (uint16_t)(u >> 16);
}

// Pre-kernel: x2 [H][S][D] fp32  ->  x2t [H][D][S] bf16 (k-contiguous rows)
__global__ __launch_bounds__(256) void vtrans_kernel(const float* __restrict__ x2,
                                                     uint16_t* __restrict__ x2t) {
  __shared__ float t[D_][64 + 1];  // +1 pad: bank-conflict-free transpose
  const int h  = blockIdx.x >> 5;
  const int k0 = (blockIdx.x & 31) << 6;  // 64-k tile
  const float* src = x2 + ((size_t)h * S_ + k0) * D_;
#pragma unroll
  for (int p = 0; p < 4; ++p) {
    int flat = p * 1024 + threadIdx.x * 4;
    int k = flat >> 6, d = flat & 63;
    float4 v = *(const float4*)(src + (size_t)k * D_ + d);
    t[d + 0][k] = v.x; t[d + 1][k] = v.y; t[d + 2][k] = v.z; t[d + 3][k] = v.w;
  }
  __syncthreads();
  uint16_t* dst = x2t + (size_t)h * D_ * S_ + k0;
#pragma unroll
  for (int p = 0; p < 4; ++p) {
    int flat = p * 1024 + threadIdx.x * 4;
    int d = flat >> 6, k = flat & 63;
    ushort4 o;
    o.x = f2bf(t[d][k + 0]); o.y = f2bf(t[d][k + 1]);
    o.z = f2bf(t[d][k + 2]); o.w = f2bf(t[d][k + 3]);
    *(ushort4*)(dst + (size_t)d * S_ + k) = o;
  }
}

// ---------------- main kernel: QT=128 rows, 512 threads, 8 waves ----------------
__global__ __launch_bounds__(512) void smm_q128(const float* __restrict__ x1,
                                                const uint16_t* __restrict__ x2t,
                                                float* __restrict__ out) {
  __shared__ __attribute__((aligned(16))) uint16_t pT[QT][KT];  // 32KB, swizzled
  __shared__ __attribute__((aligned(16))) uint16_t vT[D_][KT];  // 16KB, swizzled

  // bijective XCD swizzle: 256 blocks = 8 XCDs x 32 contiguous (2 heads/XCD)
  const int bid  = ((int)blockIdx.x & 7) * 32 + ((int)blockIdx.x >> 3);
  const int tid  = threadIdx.x;
  const int lane = tid & 63;
  const int w    = tid >> 6;          // wave 0..7 -> rows [16w,16w+16)
  const int h    = bid >> 4;          // 16 row-blocks per head
  const int q0   = (bid & 15) * QT;

  f32x4 acc[4];                        // D[16 x 64] per wave, 4 col-tiles
  f32x4 accS;                          // ones-column tile -> row sums in col 0
#pragma unroll
  for (int c = 0; c < 4; ++c) acc[c] = (f32x4){0.f, 0.f, 0.f, 0.f};
  accS = (f32x4){0.f, 0.f, 0.f, 0.f};

  // constant B fragment: B1[k][col] = (col == 0) ? 1 : 0
  bf16x8 ones;
  {
    short v = ((lane & 15) == 0) ? (short)0x3F80 : (short)0;
#pragma unroll
    for (int e = 0; e < 8; ++e) ones[e] = v;
  }

  const float* x1p = x1 + ((size_t)h * S_ + q0) * S_;
  const int prow = tid >> 5;           // 0..15 (x1 staging row base)
  const int pk4  = (tid & 31) << 2;    // 0..124 (float4 column)
  const int arow = lane & 15;          // row/col within 16-tile
  const int kgrp = lane >> 4;          // 0..3 (8-k group)

  for (int kt = 0; kt < NT; ++kt) {
    __syncthreads();  // WAR: previous iter's fragment reads done before overwrite

    // ---- stage probs: load x1 coalesced, exp, bf16, swizzled LDS write ----
#pragma unroll
    for (int p = 0; p < 8; ++p) {
      int r = prow + p * 16;
      float4 v = *(const float4*)(x1p + (size_t)r * S_ + kt * KT + pk4);
      uint32_t lo = (uint32_t)f2bf(__expf(v.x)) | ((uint32_t)f2bf(__expf(v.y)) << 16);
      uint32_t hi = (uint32_t)f2bf(__expf(v.z)) | ((uint32_t)f2bf(__expf(v.w)) << 16);
      int byteoff = (pk4 * 2) ^ ((r & 15) << 4);   // XOR swizzle (16B slots)
      *(uint2*)((char*)(&pT[r][0]) + byteoff) = make_uint2(lo, hi);
    }

    // ---- stage V^T tile [64 d][128 k] bf16 (2 x uint4 per thread) ----
    {
      const uint16_t* vp = x2t + (size_t)h * D_ * S_ + kt * KT;
#pragma unroll
      for (int p = 0; p < 2; ++p) {
        int flat = p * 512 + tid;
        int dd = flat >> 4;            // 0..63
        int ch = flat & 15;            // 16B chunk (8 bf16)
        uint4 v = *(const uint4*)(vp + (size_t)dd * S_ + ch * 8);
        int byteoff = (ch * 16) ^ ((dd & 15) << 4);
        *(uint4*)((char*)(&vT[dd][0]) + byteoff) = v;
      }
    }
    __syncthreads();

    // ---- MFMA: A = pT rows [16w..16w+16), B = vT cols, K = 128 (4 steps) ----
#pragma unroll
    for (int ks = 0; ks < 4; ++ks) {
      int kb = ks * 64 + kgrp * 16;    // byte offset within LDS row
      int ar = w * 16 + arow;
      bf16x8 a = *(const bf16x8*)((const char*)(&pT[ar][0]) + (kb ^ (arow << 4)));
      accS = __builtin_amdgcn_mfma_f32_16x16x32_bf16(a, ones, accS, 0, 0, 0);
#pragma unroll
      for (int c = 0; c < 4; ++c) {
        int bc = c * 16 + arow;
        bf16x8 b = *(const bf16x8*)((const char*)(&vT[bc][0]) + (kb ^ (arow << 4)));
        acc[c] = __builtin_amdgcn_mfma_f32_16x16x32_bf16(a, b, acc[c], 0, 0, 0);
      }
    }
  }

  // ---- epilogue: normalize by row sum, store fp32 ----
  // D layout: col = lane&15, row = (lane>>4)*4 + reg  [refcheck-verified R1]
  float* op = out + ((size_t)h * S_ + q0 + w * 16) * D_;
#pragma unroll
  for (int j = 0; j < 4; ++j) {
    float s = __shfl(accS[j], lane & 48);  // col-0 holder of this 16-lane group
    float rs = 1.0f / s;
    int row = (lane >> 4) * 4 + j;
#pragma unroll
    for (int c = 0; c < 4; ++c) {
      op[(size_t)row * D_ + c * 16 + (lane & 15)] = acc[c][j] * rs;
    }
  }
}

// ---------------- fallback (tiny workspace): R1 LDS kernel, no x2t ----------------
__global__ __launch_bounds__(256) void smm_lds(const float* __restrict__ x1,
                                               const float* __restrict__ x2,
                                               float* __restrict__ out) {
  __shared__ __attribute__((aligned(16))) uint16_t pT[QTF][KT];
  __shared__ __attribute__((aligned(16))) uint16_t vT[D_][KT];

  const int tid  = threadIdx.x;
  const int lane = tid & 63;
  const int w    = tid >> 6;
  const int h    = blockIdx.x >> 5;
  const int q0   = (blockIdx.x & 31) * QTF;

  f32x4 acc[4];
  f32x4 accS;
#pragma unroll
  for (int c = 0; c < 4; ++c) acc[c] = (f32x4){0.f, 0.f, 0.f, 0.f};
  accS = (f32x4){0.f, 0.f, 0.f, 0.f};

  bf16x8 ones;
  {
    short v = ((lane & 15) == 0) ? (short)0x3F80 : (short)0;
#pragma unroll
    for (int e = 0; e < 8; ++e) ones[e] = v;
  }

  const float* x1p = x1 + ((size_t)h * S_ + q0) * S_;
  const int prow = tid >> 5;
  const int pk4  = (tid & 31) << 2;
  const int arow = lane & 15;
  const int kgrp = lane >> 4;

  for (int kt = 0; kt < NT; ++kt) {
    __syncthreads();
#pragma unroll
    for (int p = 0; p < 8; ++p) {
      int r = prow + p * 8;
      float4 v = *(const float4*)(x1p + (size_t)r * S_ + kt * KT + pk4);
      uint32_t lo = (uint32_t)f2bf(__expf(v.x)) | ((uint32_t)f2bf(__expf(v.y)) << 16);
      uint32_t hi = (uint32_t)f2bf(__expf(v.z)) | ((uint32_t)f2bf(__expf(v.w)) << 16);
      int byteoff = (pk4 * 2) ^ ((r & 15) << 4);
      *(uint2*)((char*)(&pT[r][0]) + byteoff) = make_uint2(lo, hi);
    }
    {
      int dd = tid & 63;
      int kgq = tid >> 6;
      const float* src = x2 + ((size_t)h * S_ + kt * KT) * D_ + dd;
#pragma unroll
      for (int p = 0; p < 4; ++p) {
        int kb = p * 32 + kgq * 8;
        uint16_t tmp[8];
#pragma unroll
        for (int j = 0; j < 8; ++j) tmp[j] = f2bf(src[(size_t)(kb + j) * D_]);
        int byteoff = (kb * 2) ^ ((dd & 15) << 4);
        *(uint4*)((char*)(&vT[dd][0]) + byteoff) = *(uint4*)tmp;
      }
    }
    __syncthreads();
#pragma unroll
    for (int ks = 0; ks < 4; ++ks) {
      int kb = ks * 64 + kgrp * 16;
      int ar = w * 16 + arow;
      bf16x8 a = *(const bf16x8*)((const char*)(&pT[ar][0]) + (kb ^ (arow << 4)));
      accS = __builtin_amdgcn_mfma_f32_16x16x32_bf16(a, ones, accS, 0, 0, 0);
#pragma unroll
      for (int c = 0; c < 4; ++c) {
        int bc = c * 16 + arow;
        bf16x8 b = *(const bf16x8*)((const char*)(&vT[bc][0]) + (kb ^ (arow << 4)));
        acc[c] = __builtin_amdgcn_mfma_f32_16x16x32_bf16(a, b, acc[c], 0, 0, 0);
      }
    }
  }

  float* op = out + ((size_t)h * S_ + q0 + w * 16) * D_;
#pragma unroll
  for (int j = 0; j < 4; ++j) {
    float s = __shfl(accS[j], lane & 48);
    float rs = 1.0f / s;
    int row = (lane >> 4) * 4 + j;
#pragma unroll
    for (int c = 0; c < 4; ++c) {
      op[(size_t)row * D_ + c * 16 + (lane & 15)] = acc[c][j] * rs;
    }
  }
}

extern "C" void kernel_launch(void* const* d_in, const int* in_sizes, int n_in,
                              void* d_out, int out_size, void* d_ws, size_t ws_size,
                              hipStream_t stream) {
  const float* x1 = (const float*)d_in[0];
  const float* x2 = (const float*)d_in[1];
  float* out      = (float*)d_out;
  uint16_t* x2t   = (uint16_t*)d_ws;

  const size_t need = (size_t)H_ * D_ * S_ * sizeof(uint16_t);  // 4 MiB
  if (ws_size >= need) {
    vtrans_kernel<<<dim3(H_ * (S_ / 64)), dim3(256), 0, stream>>>(x2, x2t);
    smm_q128<<<dim3(H_ * (S_ / QT)), dim3(512), 0, stream>>>(x1, x2t, out);
  } else {
    smm_lds<<<dim3(H_ * (S_ / QTF)), dim3(256), 0, stream>>>(x1, x2, out);
  }
}